// Round 1
// baseline (146.204 us; speedup 1.0000x reference)
//
#include <hip/hip_runtime.h>
#include <hip/hip_bf16.h>
#include <math.h>

#define BB 32
#define SS 20
#define LL 50
#define NN 40000
#define DD 64

// Output layout (flat f32): scores (B,S,N) | hu (B,D) | hc (B,S,D) | attn (B,S,N)
#define OFF_SCORES 0
#define OFF_HU     (BB * SS * NN)                 // 25,600,000
#define OFF_HC     (OFF_HU + BB * DD)             // 25,602,048
#define OFF_ATTN   (OFF_HC + BB * SS * DD)        // 25,643,008

// ---------------------------------------------------------------------------
// Kernel A: per-batch prep. One block per b, 256 threads (4 waves).
// Computes hu[b][64] and hc[b][20][64], writes them into d_out.
// ---------------------------------------------------------------------------
__global__ __launch_bounds__(256) void prep_kernel(
    const int* __restrict__ user_ids,
    const int* __restrict__ sess_item,
    const int* __restrict__ rcnt_item,
    const float* __restrict__ item_emb,
    const float* __restrict__ user_emb,
    const float* __restrict__ user_emb2,
    const float* __restrict__ ue_w1,
    const float* __restrict__ ue_b1,
    const float* __restrict__ ue_w2,
    const float* __restrict__ ue_b2,
    const float* __restrict__ uenc_w,
    const float* __restrict__ uenc_b,
    const float* __restrict__ pred_w,
    const float* __restrict__ pred_b,
    float* __restrict__ out)
{
    const int b    = blockIdx.x;
    const int tid  = threadIdx.x;
    const int lane = tid & 63;
    const int wv   = tid >> 6;

    __shared__ float uemb_s[DD];
    __shared__ float u2_s[DD];
    __shared__ float hs_s[LL][DD];
    __shared__ float wraw_s[LL];
    __shared__ float wn_s[LL];
    __shared__ float part_s[4][DD];
    __shared__ float hr_s[DD];
    __shared__ float e_s[SS][DD + 1];   // +1 pad: lanes index rows -> avoid bank conflicts
    __shared__ float a_tmp[4][SS];

    // ---- phase 1: gather embeddings into LDS ----
    const int uid = user_ids[b];
    if (tid < DD) {
        uemb_s[tid] = user_emb[(size_t)uid * DD + tid];
        u2_s[tid]   = user_emb2[(size_t)uid * DD + tid];
    }
    for (int t = tid; t < LL * DD; t += 256) {
        int l = t >> 6, d = t & 63;
        int idx = rcnt_item[b * LL + l];
        hs_s[l][d] = item_emb[(size_t)idx * DD + d];
    }
    for (int t = tid; t < SS * DD; t += 256) {
        int s = t >> 6, d = t & 63;
        int idx = sess_item[b * SS + s];
        e_s[s][d] = item_emb[(size_t)idx * DD + d];
    }
    __syncthreads();

    // ---- phase 2: attention MLP, w_l raw logits. lane j = hidden unit. ----
    float pu = 0.f;
    #pragma unroll 8
    for (int i = 0; i < DD; ++i) pu += uemb_s[i] * ue_w1[i * DD + lane];
    const float b1j = ue_b1[lane];
    const float w2j = ue_w2[lane];
    const float b2  = ue_b2[0];
    for (int l = wv; l < LL; l += 4) {
        float acc = pu + b1j;
        #pragma unroll 8
        for (int i = 0; i < DD; ++i) acc += hs_s[l][i] * ue_w1[(DD + i) * DD + lane];
        acc = fmaxf(acc, 0.f);
        float contrib = acc * w2j;
        #pragma unroll
        for (int off = 32; off; off >>= 1) contrib += __shfl_xor(contrib, off);
        if (lane == 0) wraw_s[l] = contrib + b2;
    }
    __syncthreads();

    // ---- phase 3: masked softmax over L (wave 0) ----
    if (wv == 0) {
        float x = (lane < LL) ? wraw_s[lane] : -INFINITY;
        float m = x;
        #pragma unroll
        for (int off = 32; off; off >>= 1) m = fmaxf(m, __shfl_xor(m, off));
        float maskl = (lane < LL && rcnt_item[b * LL + lane] != 0) ? 1.f : 0.f;
        float e = (lane < LL) ? (__expf(x - m) + 1e-10f) * maskl : 0.f;
        float sum = e;
        #pragma unroll
        for (int off = 32; off; off >>= 1) sum += __shfl_xor(sum, off);
        if (lane < LL) wn_s[lane] = e / sum;
    }
    __syncthreads();

    // ---- phase 4: hr = sum_l wn_l * hs_l ----
    {
        float p = 0.f;
        for (int l = wv; l < LL; l += 4) p += wn_s[l] * hs_s[l][lane];
        part_s[wv][lane] = p;
    }
    __syncthreads();
    if (wv == 0) hr_s[lane] = part_s[0][lane] + part_s[1][lane] + part_s[2][lane] + part_s[3][lane];
    __syncthreads();

    // ---- phase 5: hu = [u2, hr] @ uenc_w + uenc_b ----
    {
        float p = 0.f;
        for (int i = wv * 32; i < wv * 32 + 32; ++i) {
            float c = (i < DD) ? u2_s[i] : hr_s[i - DD];
            p += c * uenc_w[i * DD + lane];
        }
        part_s[wv][lane] = p;
    }
    __syncthreads();
    if (wv == 0) {
        float hu = uenc_b[lane] + part_s[0][lane] + part_s[1][lane] + part_s[2][lane] + part_s[3][lane];
        out[OFF_HU + b * DD + lane] = hu;
    }

    // ---- phase 6: session self-attention -> hc ----
    for (int s = wv; s < SS; s += 4) {
        const int t = lane;
        float lt = -INFINITY;
        float maskt = 0.f;
        if (t < SS) {
            float dot = 0.f;
            #pragma unroll 8
            for (int d = 0; d < DD; ++d) dot += e_s[s][d] * e_s[t][d];
            lt = dot * 0.125f;
            maskt = (sess_item[b * SS + t] != 0) ? 1.f : 0.f;
        }
        float srow = (sess_item[b * SS + s] != 0) ? 1.f : 0.f;
        float m = lt;
        #pragma unroll
        for (int off = 32; off; off >>= 1) m = fmaxf(m, __shfl_xor(m, off));
        float e = (t < SS) ? (__expf(lt - m) + 1e-10f) * (maskt * srow) : 0.f;
        float sum = e;
        #pragma unroll
        for (int off = 32; off; off >>= 1) sum += __shfl_xor(sum, off);
        if (t < SS) a_tmp[wv][t] = e / sum;
        __syncthreads();
        float hc = 0.f;
        #pragma unroll
        for (int tt = 0; tt < SS; ++tt) hc += a_tmp[wv][tt] * e_s[tt][lane];
        out[OFF_HC + (size_t)(b * SS + s) * DD + lane] = hc;
        __syncthreads();
    }
}

// ---------------------------------------------------------------------------
// Kernel B: scores + attn over (B,S,N). One thread per (b,n); vemb row in
// registers, hc[b] in LDS (broadcast reads), nontemporal streaming stores.
// ---------------------------------------------------------------------------
__global__ __launch_bounds__(256) void score_kernel(
    const int* __restrict__ items,
    const float* __restrict__ item_emb,
    const float* __restrict__ pred_w,
    const float* __restrict__ pred_b,
    float* __restrict__ out)
{
    const int b   = blockIdx.y;
    const int tid = threadIdx.x;
    const int n   = blockIdx.x * 256 + tid;

    __shared__ __align__(16) float hc_s[SS * DD];
    __shared__ __align__(16) float hu_s[DD];
    __shared__ __align__(16) float wv_s[DD];
    __shared__ float hcwc_s[SS];
    __shared__ float c0_s;

    for (int t = tid; t < SS * DD; t += 256) hc_s[t] = out[OFF_HC + b * SS * DD + t];
    if (tid < DD) {
        hu_s[tid] = out[OFF_HU + b * DD + tid];
        wv_s[tid] = pred_w[2 * DD + tid];
    }
    __syncthreads();

    // c0 = hu . wu + pred_b  (wave 0); hcwc_s[s] = hc_s . wc  (all waves)
    if (tid < 64) {
        float p = hu_s[tid] * pred_w[tid];
        #pragma unroll
        for (int off = 32; off; off >>= 1) p += __shfl_xor(p, off);
        if (tid == 0) c0_s = p + pred_b[0];
    }
    {
        const int wvv = tid >> 6, lane = tid & 63;
        for (int s = wvv; s < SS; s += 4) {
            float p = hc_s[s * DD + lane] * pred_w[DD + lane];
            #pragma unroll
            for (int off = 32; off; off >>= 1) p += __shfl_xor(p, off);
            if (lane == 0) hcwc_s[s] = p;
        }
    }
    __syncthreads();

    if (n >= NN) return;

    const int idx = items[b * NN + n];
    const float4* __restrict__ vrow = (const float4*)(item_emb + (size_t)idx * DD);
    float4 v[16];
    #pragma unroll
    for (int c = 0; c < 16; ++c) v[c] = vrow[c];

    float vwv = 0.f, huv = 0.f;
    #pragma unroll
    for (int c = 0; c < 16; ++c) {
        const float4 w4 = ((const float4*)wv_s)[c];
        const float4 h4 = ((const float4*)hu_s)[c];
        vwv += v[c].x * w4.x + v[c].y * w4.y + v[c].z * w4.z + v[c].w * w4.w;
        huv += v[c].x * h4.x + v[c].y * h4.y + v[c].z * h4.z + v[c].w * h4.w;
    }

    const float base = c0_s + vwv;
    float* sc_out = out + OFF_SCORES + (size_t)b * SS * NN + n;
    float* at_out = out + OFF_ATTN   + (size_t)b * SS * NN + n;

    #pragma unroll
    for (int s = 0; s < SS; ++s) {
        float hcv = 0.f;
        #pragma unroll
        for (int c = 0; c < 16; ++c) {
            const float4 h4 = ((const float4*)(hc_s + s * DD))[c];
            hcv += v[c].x * h4.x + v[c].y * h4.y + v[c].z * h4.z + v[c].w * h4.w;
        }
        float g = base + hcwc_s[s];
        float attn = 1.f / (1.f + __expf(-g));
        float score = attn * huv + (1.f - attn) * hcv;
        __builtin_nontemporal_store(score, sc_out + (size_t)s * NN);
        __builtin_nontemporal_store(attn,  at_out + (size_t)s * NN);
    }
}

extern "C" void kernel_launch(void* const* d_in, const int* in_sizes, int n_in,
                              void* d_out, int out_size, void* d_ws, size_t ws_size,
                              hipStream_t stream) {
    const int*   user_ids  = (const int*)d_in[0];
    const int*   sess_item = (const int*)d_in[1];
    const int*   rcnt_item = (const int*)d_in[2];
    const int*   items     = (const int*)d_in[3];
    const float* item_emb  = (const float*)d_in[4];
    const float* user_emb  = (const float*)d_in[5];
    const float* user_emb2 = (const float*)d_in[6];
    const float* ue_w1     = (const float*)d_in[7];
    const float* ue_b1     = (const float*)d_in[8];
    const float* ue_w2     = (const float*)d_in[9];
    const float* ue_b2     = (const float*)d_in[10];
    const float* uenc_w    = (const float*)d_in[11];
    const float* uenc_b    = (const float*)d_in[12];
    const float* pred_w    = (const float*)d_in[13];
    const float* pred_b    = (const float*)d_in[14];
    float* out = (float*)d_out;

    hipLaunchKernelGGL(prep_kernel, dim3(BB), dim3(256), 0, stream,
                       user_ids, sess_item, rcnt_item, item_emb, user_emb, user_emb2,
                       ue_w1, ue_b1, ue_w2, ue_b2, uenc_w, uenc_b, pred_w, pred_b, out);

    hipLaunchKernelGGL(score_kernel, dim3((NN + 255) / 256, BB), dim3(256), 0, stream,
                       items, item_emb, pred_w, pred_b, out);
}